// Round 3
// baseline (7847.511 us; speedup 1.0000x reference)
//
#include <hip/hip_runtime.h>

#ifndef __has_builtin
#define __has_builtin(x) 0
#endif

typedef float v2f __attribute__((ext_vector_type(2)));

__device__ __forceinline__ float fast_exp2(float x) {
#if __has_builtin(__builtin_amdgcn_exp2f)
  return __builtin_amdgcn_exp2f(x);
#else
  return exp2f(x);
#endif
}
__device__ __forceinline__ float fast_rcp(float x) {
#if __has_builtin(__builtin_amdgcn_rcpf)
  return __builtin_amdgcn_rcpf(x);
#else
  return 1.0f / x;
#endif
}
__device__ __forceinline__ v2f pk_fma(v2f a, v2f b, v2f c) {
  return __builtin_elementwise_fma(a, b, c);  // v_pk_fma_f32, full-rate
}
// butterfly xor-1 add: both lanes of a pair end with the pair sum
__device__ __forceinline__ float xor1_add(float v) {
  int p = __builtin_amdgcn_ds_swizzle(__float_as_int(v), 0x041F);
  return v + __int_as_float(p);
}

namespace {
constexpr int kB = 131072;
constexpr int kSeq = 150;
constexpr int kD = 2;
constexpr int kH = 64;
constexpr int kPred = 150;
constexpr int kSteps = kPred - 1;          // 149
constexpr float kDt = 150.0f / 149.0f;     // linspace(0,150,150) spacing
constexpr float kC = 2.8853900817779268f;  // 2*log2(e)
constexpr float kClampP = 30.0f;  // p<=30 -> d<=1+2^30, D=prod4 < 1.3e36 (finite)
}  // namespace

// f(y) = tanh(y@W1+b1)@W2 + b2, folded:
//   tanh(q) = 1 - 2*r,  r = rcp(1 + exp2(C*q)),  p = C*q clamped at 30
//   acc_d = base_d + sum_j r_j*(-2*W2[j][d]),  base_d = b2[d] + sum_j W2[j][d]
// Shared rcp across each 4-unit group: R = rcp(d0*d1*d2*d3), r_i = R*prod(others).
__device__ __forceinline__ void feval_half(
    float y0, float y1, int gbase, const float4* __restrict__ swx,
    const float4* __restrict__ swy, const float4* __restrict__ sbb,
    const float4* __restrict__ swz, const float4* __restrict__ sww,
    float& f0p, float& f1p) {
  const v2f y0v = {y0, y0}, y1v = {y1, y1};
  const v2f one = {1.f, 1.f};
  v2f a0 = {0.f, 0.f}, a1 = {0.f, 0.f};
  v2f c0 = {0.f, 0.f}, c1 = {0.f, 0.f};
#pragma unroll
  for (int g = gbase; g < gbase + 8; ++g) {
    const float4 wx = swx[g], wy = swy[g], bb = sbb[g];
    v2f p01 = pk_fma(y0v, (v2f){wx.x, wx.y},
                     pk_fma(y1v, (v2f){wy.x, wy.y}, (v2f){bb.x, bb.y}));
    v2f p23 = pk_fma(y0v, (v2f){wx.z, wx.w},
                     pk_fma(y1v, (v2f){wy.z, wy.w}, (v2f){bb.z, bb.w}));
    v2f t01 = {fast_exp2(fminf(p01.x, kClampP)), fast_exp2(fminf(p01.y, kClampP))};
    v2f t23 = {fast_exp2(fminf(p23.x, kClampP)), fast_exp2(fminf(p23.y, kClampP))};
    v2f d01 = t01 + one;  // v_pk_add_f32
    v2f d23 = t23 + one;
    float m01 = d01.x * d01.y;
    float m23 = d23.x * d23.y;
    float R = fast_rcp(m01 * m23);
    float Rm23 = R * m23;  // = rcp(d0*d1)
    float Rm01 = R * m01;  // = rcp(d2*d3)
    v2f r01 = {Rm23 * d01.y, Rm23 * d01.x};
    v2f r23 = {Rm01 * d23.y, Rm01 * d23.x};
    const float4 wz = swz[g], ww = sww[g];
    a0 = pk_fma(r01, (v2f){wz.x, wz.y}, a0);
    c0 = pk_fma(r23, (v2f){wz.z, wz.w}, c0);
    a1 = pk_fma(r01, (v2f){ww.x, ww.y}, a1);
    c1 = pk_fma(r23, (v2f){ww.z, ww.w}, c1);
  }
  v2f s0 = a0 + c0;
  v2f s1 = a1 + c1;
  f0p = s0.x + s0.y;
  f1p = s1.x + s1.y;
}

// 2 lanes per batch element: lane parity selects hidden units [0,32) / [32,64).
__global__ __launch_bounds__(256, 4) void ode_kernel(
    const float* __restrict__ x, const float* __restrict__ W1,
    const float* __restrict__ b1, const float* __restrict__ W2,
    const float* __restrict__ b2, float* __restrict__ out) {
  __shared__ float4 swx[kH / 4], swy[kH / 4], sbb[kH / 4];
  __shared__ float4 swz[kH / 4], sww[kH / 4];
  __shared__ float sbase[2];

  const int t = threadIdx.x;
  if (t < kH) {
    reinterpret_cast<float*>(swx)[t] = W1[t] * kC;        // W1 (D,H) row 0
    reinterpret_cast<float*>(swy)[t] = W1[kH + t] * kC;   // W1 row 1
    reinterpret_cast<float*>(sbb)[t] = b1[t] * kC;
    reinterpret_cast<float*>(swz)[t] = -2.0f * W2[2 * t];      // W2 (H,D) col 0
    reinterpret_cast<float*>(sww)[t] = -2.0f * W2[2 * t + 1];  // col 1
  }
  if (t < 2) {
    float s = b2[t];
    for (int j = 0; j < kH; ++j) s += W2[2 * j + t];
    sbase[t] = s;
  }
  __syncthreads();
  const float base0 = sbase[0], base1 = sbase[1];

  const long gtid = (long)blockIdx.x * blockDim.x + t;
  const long elem = gtid >> 1;
  const int parity = (int)(gtid & 1);
  const int gbase = parity * 8;  // 8 float4-groups = 32 hidden units per lane

  const float* xp = x + elem * (long)(kSeq * kD) + (kSeq - 1) * kD;
  float y0 = xp[0];
  float y1 = xp[1];
  float* op = out + elem * (long)(kPred * kD);

  float py0 = y0, py1 = y1;  // state at the previous even time index
  constexpr float DT = kDt, DT3 = kDt / 3.0f, DT8 = kDt / 8.0f;

  for (int s = 1; s <= kSteps; ++s) {
    float k1x, k1y, k2x, k2y, k3x, k3y, k4x, k4y, u, v;

    feval_half(y0, y1, gbase, swx, swy, sbb, swz, sww, u, v);
    k1x = base0 + xor1_add(u);
    k1y = base1 + xor1_add(v);

    feval_half(fmaf(DT3, k1x, y0), fmaf(DT3, k1y, y1), gbase, swx, swy, sbb,
               swz, sww, u, v);
    k2x = base0 + xor1_add(u);
    k2y = base1 + xor1_add(v);

    feval_half(fmaf(DT, k2x, fmaf(-DT3, k1x, y0)),
               fmaf(DT, k2y, fmaf(-DT3, k1y, y1)), gbase, swx, swy, sbb, swz,
               sww, u, v);
    k3x = base0 + xor1_add(u);
    k3y = base1 + xor1_add(v);

    feval_half(fmaf(DT, k1x - k2x + k3x, y0), fmaf(DT, k1y - k2y + k3y, y1),
               gbase, swx, swy, sbb, swz, sww, u, v);
    k4x = base0 + xor1_add(u);
    k4y = base1 + xor1_add(v);

    y0 = fmaf(DT8, k1x + 3.0f * (k2x + k3x) + k4x, y0);
    y1 = fmaf(DT8, k1y + 3.0f * (k2y + k3y) + k4y, y1);

    if (s & 1) {
      // pair (s-1, s) ready; alternate the 16B store between the two lanes
      if (((s >> 1) & 1) == parity) {
        float4 w = make_float4(py0, py1, y0, y1);
        *reinterpret_cast<float4*>(op + (long)(s - 1) * 2) = w;
      }
    } else {
      py0 = y0;
      py1 = y1;
    }
  }
}

extern "C" void kernel_launch(void* const* d_in, const int* in_sizes, int n_in,
                              void* d_out, int out_size, void* d_ws,
                              size_t ws_size, hipStream_t stream) {
  const float* x = (const float*)d_in[0];
  const float* W1 = (const float*)d_in[1];
  const float* b1 = (const float*)d_in[2];
  const float* W2 = (const float*)d_in[3];
  const float* b2 = (const float*)d_in[4];
  float* out = (float*)d_out;

  dim3 grid((kB * 2) / 256);  // 2 lanes per element
  dim3 block(256);
  hipLaunchKernelGGL(ode_kernel, grid, block, 0, stream, x, W1, b1, W2, b2,
                     out);
}